// Round 2
// baseline (1846.866 us; speedup 1.0000x reference)
//
#include <hip/hip_runtime.h>

// SwinTransformerBlock: B=8, H=W=256, C=48, NH=3, WS=8, SS=4, N=64, HID=192, SE_R=16
// All in/out buffers fp32 (per reference dtypes).

// ---------------- kernel 0: transpose fc2_w (48x192) -> (192x48) ----------------
__global__ __launch_bounds__(256) void transpose_fc2(
    const float* __restrict__ w, float* __restrict__ wt)
{
    int idx = blockIdx.x * 256 + threadIdx.x;
    if (idx < 192 * 48) {
        int o = idx / 48, c = idx - o * 48;
        wt[o * 48 + c] = w[c * 192 + o];
    }
}

// ---------------- kernel 1: per-window LN1+shift+attn+SE+proj+residual ----------------
__global__ __launch_bounds__(256, 2) void win_kernel(
    const float* __restrict__ x,
    const float* __restrict__ gamma1,
    const float* __restrict__ beta1,
    const float* __restrict__ qkv_w,
    const float* __restrict__ qkv_b,
    const float* __restrict__ rpb_t,
    const float* __restrict__ wf,
    const float* __restrict__ se_w1,
    const float* __restrict__ se_b1,
    const float* __restrict__ se_w2,
    const float* __restrict__ se_b2,
    const float* __restrict__ proj_w,
    const float* __restrict__ proj_b,
    float* __restrict__ out)
{
    __shared__ float xw[64][48];     // LN'd window tokens
    __shared__ float qk[144][64];    // [o][t] : o = sel*48 + h*16 + d  (q rows pre-scaled)
    __shared__ float ao[64][48];     // attention output (then +SE)
    __shared__ float rpb_s[675];     // rel-pos-bias table (225 x 3)
    __shared__ float se_buf[48];
    __shared__ float se1[4];
    __shared__ int   reg_id[64];
    __shared__ int   gidx[64];

    const int tid = threadIdx.x;
    const int w  = blockIdx.x;
    const int b  = w >> 10;
    const int wi = (w >> 5) & 31;
    const int wj = w & 31;

    for (int i = tid; i < 675; i += 256) rpb_s[i] = rpb_t[i];

    // ---- LN1 + shifted gather (thread t = token) ----
    if (tid < 64) {
        const int t = tid, ti = t >> 3, tj = t & 7;
        const int si = wi * 8 + ti, sj = wj * 8 + tj;      // coords in shifted frame
        const int oi = (si + 4) & 255, oj = (sj + 4) & 255; // original coords
        const int g = (b << 16) + (oi << 8) + oj;
        gidx[t] = g;
        const int rr = si < 248 ? 0 : (si < 252 ? 1 : 2);
        const int rc = sj < 248 ? 0 : (sj < 252 ? 1 : 2);
        reg_id[t] = rr * 3 + rc;

        float v[48];
        const float4* p4 = reinterpret_cast<const float4*>(x + (size_t)g * 48);
        #pragma unroll
        for (int i = 0; i < 12; ++i) reinterpret_cast<float4*>(v)[i] = p4[i];
        float mu = 0.f;
        #pragma unroll
        for (int c = 0; c < 48; ++c) mu += v[c];
        mu *= (1.f / 48.f);
        float var = 0.f;
        #pragma unroll
        for (int c = 0; c < 48; ++c) { float d = v[c] - mu; var += d * d; }
        var *= (1.f / 48.f);
        const float rs = rsqrtf(var + 1e-5f);
        #pragma unroll
        for (int c = 0; c < 48; ++c)
            xw[t][c] = (v[c] - mu) * rs * gamma1[c] + beta1[c];
    }
    __syncthreads();

    // ---- qkv = xw @ qkv_w.T + qkv_b  (9216 outputs) ----
    for (int idx = tid; idx < 144 * 64; idx += 256) {
        const int o = idx >> 6;
        const int t = idx & 63;
        float wv[48];
        const float4* w4 = reinterpret_cast<const float4*>(qkv_w + o * 48);
        #pragma unroll
        for (int i = 0; i < 12; ++i) reinterpret_cast<float4*>(wv)[i] = w4[i];
        float s = qkv_b[o];
        #pragma unroll
        for (int c = 0; c < 48; ++c) s += xw[t][c] * wv[c];
        if (o < 48) s *= 0.25f;   // q * scale (hd^-0.5)
        qk[o][t] = s;
    }
    __syncthreads();

    // ---- attention: thread = (head, row); single pass, no max-subtract (scores tiny) ----
    if (tid < 192) {
        const int h = tid >> 6;
        const int n = tid & 63;
        float qr[16];
        #pragma unroll
        for (int d = 0; d < 16; ++d) qr[d] = qk[h * 16 + d][n];
        const int i_n = n >> 3, j_n = n & 7;
        const int rn = reg_id[n];
        float sum = 0.f, acc[16];
        #pragma unroll
        for (int d = 0; d < 16; ++d) acc[d] = 0.f;
        for (int m = 0; m < 64; ++m) {
            float s = 0.f;
            #pragma unroll
            for (int d = 0; d < 16; ++d) s += qr[d] * qk[48 + h * 16 + d][m];
            const int i_m = m >> 3, j_m = m & 7;
            s += rpb_s[((i_n - i_m + 7) * 15 + (j_n - j_m + 7)) * 3 + h];
            if (reg_id[m] != rn) s -= 100.f;   // shifted-window mask
            const float p = __expf(s);
            sum += p;
            #pragma unroll
            for (int d = 0; d < 16; ++d) acc[d] += p * qk[96 + h * 16 + d][m];
        }
        const float inv = 1.f / sum;
        #pragma unroll
        for (int d = 0; d < 16; ++d) ao[n][h * 16 + d] = acc[d] * inv;
    }
    __syncthreads();

    // ---- SE: mean over tokens -> fc(48->3) relu -> fc(3->48) sigmoid ----
    if (tid < 48) {
        float s = 0.f;
        #pragma unroll
        for (int t = 0; t < 64; ++t) s += xw[t][tid];
        se_buf[tid] = s * (1.f / 64.f);
    }
    __syncthreads();
    if (tid < 3) {
        float s = se_b1[tid];
        #pragma unroll
        for (int c = 0; c < 48; ++c) s += se_buf[c] * se_w1[tid * 48 + c];
        se1[tid] = fmaxf(s, 0.f);
    }
    __syncthreads();
    if (tid < 48) {
        float s = se_b2[tid];
        #pragma unroll
        for (int r = 0; r < 3; ++r) s += se1[r] * se_w2[tid * 3 + r];
        const float sig = 1.f / (1.f + __expf(-s));
        se_buf[tid] = sig * wf[0];   // fold weight_factor
    }
    __syncthreads();

    // ---- out += wf * xw * se ----
    for (int idx = tid; idx < 64 * 48; idx += 256) {
        const int t = idx / 48, c = idx - t * 48;
        ao[t][c] += se_buf[c] * xw[t][c];
    }
    __syncthreads();

    // ---- proj + residual + scatter (window-reverse + unshift) ----
    for (int idx = tid; idx < 64 * 48; idx += 256) {
        const int t = idx / 48, c = idx - t * 48;
        float wv[48];
        const float4* w4 = reinterpret_cast<const float4*>(proj_w + c * 48);
        #pragma unroll
        for (int i = 0; i < 12; ++i) reinterpret_cast<float4*>(wv)[i] = w4[i];
        float s = proj_b[c];
        #pragma unroll
        for (int o = 0; o < 48; ++o) s += ao[t][o] * wv[o];
        const size_t gi = (size_t)gidx[t] * 48 + c;
        out[gi] = x[gi] + s;
    }
}

// ---------------- kernel 2: per-token LN2 + MLP(48->192 gelu ->48) + residual, in-place ----------------
__global__ __launch_bounds__(256) void mlp_kernel(
    float* __restrict__ xio,
    const float* __restrict__ gamma2,
    const float* __restrict__ beta2,
    const float* __restrict__ fc1_w,
    const float* __restrict__ fc1_b,
    const float* __restrict__ w2t,   // fc2_w transposed (192x48)
    const float* __restrict__ fc2_b)
{
    const size_t g = (size_t)blockIdx.x * 256 + threadIdx.x;   // token id < 524288
    float* p = xio + g * 48;
    const float4* p4 = reinterpret_cast<const float4*>(p);

    float xv[48];
    #pragma unroll
    for (int i = 0; i < 12; ++i) reinterpret_cast<float4*>(xv)[i] = p4[i];

    float a[48];
    float mu = 0.f;
    #pragma unroll
    for (int c = 0; c < 48; ++c) mu += xv[c];
    mu *= (1.f / 48.f);
    float var = 0.f;
    #pragma unroll
    for (int c = 0; c < 48; ++c) { float d = xv[c] - mu; var += d * d; }
    var *= (1.f / 48.f);
    const float rs = rsqrtf(var + 1e-5f);
    #pragma unroll
    for (int c = 0; c < 48; ++c) a[c] = (xv[c] - mu) * rs * gamma2[c] + beta2[c];

    float acc[48];
    #pragma unroll
    for (int c = 0; c < 48; ++c) acc[c] = fc2_b[c];

    for (int o = 0; o < 192; ++o) {
        const float4* w4 = reinterpret_cast<const float4*>(fc1_w + o * 48);
        float s = fc1_b[o];
        #pragma unroll
        for (int i = 0; i < 12; ++i) {
            float4 wv = w4[i];
            s += a[i * 4 + 0] * wv.x + a[i * 4 + 1] * wv.y
               + a[i * 4 + 2] * wv.z + a[i * 4 + 3] * wv.w;
        }
        const float ge = 0.5f * s * (1.f + erff(s * 0.70710678118654752f));  // exact gelu
        const float4* u4 = reinterpret_cast<const float4*>(w2t + o * 48);
        #pragma unroll
        for (int i = 0; i < 12; ++i) {
            float4 wv = u4[i];
            acc[i * 4 + 0] += ge * wv.x;
            acc[i * 4 + 1] += ge * wv.y;
            acc[i * 4 + 2] += ge * wv.z;
            acc[i * 4 + 3] += ge * wv.w;
        }
    }

    // residual + store, vectorized
    float4* o4 = reinterpret_cast<float4*>(p);
    #pragma unroll
    for (int i = 0; i < 12; ++i) {
        float4 u;
        u.x = xv[i * 4 + 0] + acc[i * 4 + 0];
        u.y = xv[i * 4 + 1] + acc[i * 4 + 1];
        u.z = xv[i * 4 + 2] + acc[i * 4 + 2];
        u.w = xv[i * 4 + 3] + acc[i * 4 + 3];
        o4[i] = u;
    }
}

extern "C" void kernel_launch(void* const* d_in, const int* in_sizes, int n_in,
                              void* d_out, int out_size, void* d_ws, size_t ws_size,
                              hipStream_t stream)
{
    (void)in_sizes; (void)n_in; (void)out_size; (void)ws_size;
    const float* x      = (const float*)d_in[0];
    const float* gamma1 = (const float*)d_in[1];
    const float* beta1  = (const float*)d_in[2];
    const float* qkv_w  = (const float*)d_in[3];
    const float* qkv_b  = (const float*)d_in[4];
    const float* rpb_t  = (const float*)d_in[5];
    const float* wf     = (const float*)d_in[6];
    const float* se_w1  = (const float*)d_in[7];
    const float* se_b1  = (const float*)d_in[8];
    const float* se_w2  = (const float*)d_in[9];
    const float* se_b2  = (const float*)d_in[10];
    const float* proj_w = (const float*)d_in[11];
    const float* proj_b = (const float*)d_in[12];
    const float* gamma2 = (const float*)d_in[13];
    const float* beta2  = (const float*)d_in[14];
    const float* fc1_w  = (const float*)d_in[15];
    const float* fc1_b  = (const float*)d_in[16];
    const float* fc2_w  = (const float*)d_in[17];
    const float* fc2_b  = (const float*)d_in[18];
    float* out = (float*)d_out;
    float* w2t = (float*)d_ws;

    transpose_fc2<<<36, 256, 0, stream>>>(fc2_w, w2t);
    win_kernel<<<8192, 256, 0, stream>>>(x, gamma1, beta1, qkv_w, qkv_b, rpb_t, wf,
                                         se_w1, se_b1, se_w2, se_b2, proj_w, proj_b, out);
    mlp_kernel<<<2048, 256, 0, stream>>>(out, gamma2, beta2, fc1_w, fc1_b, w2t, fc2_b);
}

// Round 3
// 795.583 us; speedup vs baseline: 2.3214x; 2.3214x over previous
//
#include <hip/hip_runtime.h>

// SwinTransformerBlock: B=8, H=W=256, C=48, NH=3, WS=8, SS=4, N=64, HID=192
// fp32 in/out; attention path fp32 vector; MLP path bf16 MFMA.

typedef short bfrag __attribute__((ext_vector_type(8)));   // 8 bf16 (4 VGPRs)
typedef float f32x4 __attribute__((ext_vector_type(4)));

__device__ __forceinline__ unsigned short f2bf(float f) {
    union { float f; unsigned u; } v; v.f = f;
    unsigned r = v.u + 0x7fffu + ((v.u >> 16) & 1u);   // RNE
    return (unsigned short)(r >> 16);
}

// ---------------- kernel 0: convert MLP weights to bf16 in d_ws ----------------
// w1p[192][64]  : fc1_w rows zero-padded K 48->64
// w2p[48][192]  : fc2_w rows as-is (already Bt[n][k] layout)
__global__ __launch_bounds__(256) void prep_weights(
    const float* __restrict__ fc1_w, const float* __restrict__ fc2_w,
    unsigned short* __restrict__ ws)
{
    int idx = blockIdx.x * 256 + threadIdx.x;
    if (idx < 192 * 64) {
        int o = idx >> 6, k = idx & 63;
        ws[idx] = (k < 48) ? f2bf(fc1_w[o * 48 + k]) : 0;
    } else if (idx < 192 * 64 + 48 * 192) {
        int j = idx - 192 * 64;
        ws[idx] = f2bf(fc2_w[j]);
    }
}

// ---------------- kernel 1: per-window LN1+shift+attn+SE+proj+residual ----------------
__global__ __launch_bounds__(256, 3) void win_kernel(
    const float* __restrict__ x,
    const float* __restrict__ gamma1,
    const float* __restrict__ beta1,
    const float* __restrict__ qkv_w,
    const float* __restrict__ qkv_b,
    const float* __restrict__ rpb_t,
    const float* __restrict__ wf,
    const float* __restrict__ se_w1,
    const float* __restrict__ se_b1,
    const float* __restrict__ se_w2,
    const float* __restrict__ se_b2,
    const float* __restrict__ proj_w,
    const float* __restrict__ proj_b,
    float* __restrict__ out)
{
    __shared__ float xw[64][49];     // LN'd window tokens (padded stride)
    __shared__ float qk[144][64];    // [o][t]; reused as ao[64][49] after attention
    __shared__ float rpb_s[675];
    __shared__ float se_buf[48];
    __shared__ float se1[4];
    __shared__ int   reg_id[64];
    __shared__ int   gidx[64];

    const int tid = threadIdx.x;
    const int w  = blockIdx.x;
    const int b  = w >> 10;
    const int wi = (w >> 5) & 31;
    const int wj = w & 31;

    for (int i = tid; i < 675; i += 256) rpb_s[i] = rpb_t[i];

    // ---- LN1 + shifted gather (thread t = token) ----
    if (tid < 64) {
        const int t = tid, ti = t >> 3, tj = t & 7;
        const int si = wi * 8 + ti, sj = wj * 8 + tj;
        const int oi = (si + 4) & 255, oj = (sj + 4) & 255;
        const int g = (b << 16) + (oi << 8) + oj;
        gidx[t] = g;
        const int rr = si < 248 ? 0 : (si < 252 ? 1 : 2);
        const int rc = sj < 248 ? 0 : (sj < 252 ? 1 : 2);
        reg_id[t] = rr * 3 + rc;

        float v[48];
        const float4* p4 = reinterpret_cast<const float4*>(x + (size_t)g * 48);
        #pragma unroll
        for (int i = 0; i < 12; ++i) reinterpret_cast<float4*>(v)[i] = p4[i];
        float mu = 0.f;
        #pragma unroll
        for (int c = 0; c < 48; ++c) mu += v[c];
        mu *= (1.f / 48.f);
        float var = 0.f;
        #pragma unroll
        for (int c = 0; c < 48; ++c) { float d = v[c] - mu; var += d * d; }
        var *= (1.f / 48.f);
        const float rs = rsqrtf(var + 1e-5f);
        #pragma unroll
        for (int c = 0; c < 48; ++c)
            xw[t][c] = (v[c] - mu) * rs * gamma1[c] + beta1[c];
    }
    __syncthreads();

    // ---- qkv = xw @ qkv_w.T + qkv_b (o wave-uniform -> scalar weight loads) ----
    for (int idx = tid; idx < 144 * 64; idx += 256) {
        const int o = __builtin_amdgcn_readfirstlane(idx >> 6);
        const int t = idx & 63;
        float wv[48];
        const float4* w4 = reinterpret_cast<const float4*>(qkv_w + o * 48);
        #pragma unroll
        for (int i = 0; i < 12; ++i) reinterpret_cast<float4*>(wv)[i] = w4[i];
        float s = qkv_b[o];
        #pragma unroll
        for (int c = 0; c < 48; ++c) s += xw[t][c] * wv[c];
        if (o < 48) s *= 0.25f;   // q * scale
        qk[o][t] = s;
    }
    __syncthreads();

    // ---- attention: thread = (head, row); single pass (scores bounded) ----
    float accr[16]; float inv = 0.f; int hn = 0, nn = 0;
    if (tid < 192) {
        const int h = tid >> 6;
        const int n = tid & 63;
        hn = h; nn = n;
        float qr[16];
        #pragma unroll
        for (int d = 0; d < 16; ++d) qr[d] = qk[h * 16 + d][n];
        const int i_n = n >> 3, j_n = n & 7;
        const int rn = reg_id[n];
        float sum = 0.f;
        #pragma unroll
        for (int d = 0; d < 16; ++d) accr[d] = 0.f;
        for (int m = 0; m < 64; ++m) {
            float s = 0.f;
            #pragma unroll
            for (int d = 0; d < 16; ++d) s += qr[d] * qk[48 + h * 16 + d][m];
            const int i_m = m >> 3, j_m = m & 7;
            s += rpb_s[((i_n - i_m + 7) * 15 + (j_n - j_m + 7)) * 3 + h];
            if (reg_id[m] != rn) s -= 100.f;
            const float p = __expf(s);
            sum += p;
            #pragma unroll
            for (int d = 0; d < 16; ++d) accr[d] += p * qk[96 + h * 16 + d][m];
        }
        inv = 1.f / sum;
    }
    __syncthreads();                       // all k/v reads done
    float* aof = &qk[0][0];                // overlay ao[64][49] on qk
    if (tid < 192) {
        #pragma unroll
        for (int d = 0; d < 16; ++d) aof[nn * 49 + hn * 16 + d] = accr[d] * inv;
    }
    __syncthreads();

    // ---- SE ----
    if (tid < 48) {
        float s = 0.f;
        #pragma unroll
        for (int t = 0; t < 64; ++t) s += xw[t][tid];
        se_buf[tid] = s * (1.f / 64.f);
    }
    __syncthreads();
    if (tid < 3) {
        float s = se_b1[tid];
        #pragma unroll
        for (int c = 0; c < 48; ++c) s += se_buf[c] * se_w1[tid * 48 + c];
        se1[tid] = fmaxf(s, 0.f);
    }
    __syncthreads();
    if (tid < 48) {
        float s = se_b2[tid];
        #pragma unroll
        for (int r = 0; r < 3; ++r) s += se1[r] * se_w2[tid * 3 + r];
        se_buf[tid] = (1.f / (1.f + __expf(-s))) * wf[0];
    }
    __syncthreads();

    // ---- ao += wf*sig * xw ----
    for (int idx = tid; idx < 64 * 48; idx += 256) {
        const int t = idx / 48, c = idx - t * 48;
        aof[t * 49 + c] += se_buf[c] * xw[t][c];
    }
    __syncthreads();

    // ---- proj + residual + scatter ----
    for (int idx = tid; idx < 64 * 48; idx += 256) {
        const int t = idx / 48, c = idx - t * 48;
        float wv[48];
        const float4* w4 = reinterpret_cast<const float4*>(proj_w + c * 48);
        #pragma unroll
        for (int i = 0; i < 12; ++i) reinterpret_cast<float4*>(wv)[i] = w4[i];
        float s = proj_b[c];
        #pragma unroll
        for (int o = 0; o < 48; ++o) s += aof[t * 49 + o] * wv[o];
        const size_t gi = (size_t)gidx[t] * 48 + c;
        out[gi] = x[gi] + s;
    }
}

// ---------------- kernel 2: MLP via bf16 MFMA, in-place on out ----------------
// per block: 64 tokens. LN2 fp32 -> bf16 -> fc1 (K=48 pad 64) -> gelu -> fc2 (K=192) -> +residual
__global__ __launch_bounds__(256, 4) void mlp_mfma(
    float* __restrict__ xio,
    const float* __restrict__ gamma2,
    const float* __restrict__ beta2,
    const unsigned short* __restrict__ w1,   // [192][64] bf16, K zero-padded
    const unsigned short* __restrict__ w2,   // [48][192] bf16
    const float* __restrict__ fc1_b,
    const float* __restrict__ fc2_b)
{
    __shared__ __align__(16) unsigned short aB[64][72];    // LN'd tokens, k 48..63 zero
    __shared__ __align__(16) unsigned short hB[64][200];   // gelu(fc1) bf16
    const int tid = threadIdx.x;
    const size_t tok0 = (size_t)blockIdx.x * 64;

    // ---- LN2 ----
    if (tid < 64) {
        const float* p = xio + (tok0 + tid) * 48;
        float v[48];
        const float4* p4 = reinterpret_cast<const float4*>(p);
        #pragma unroll
        for (int i = 0; i < 12; ++i) reinterpret_cast<float4*>(v)[i] = p4[i];
        float mu = 0.f;
        #pragma unroll
        for (int c = 0; c < 48; ++c) mu += v[c];
        mu *= (1.f / 48.f);
        float var = 0.f;
        #pragma unroll
        for (int c = 0; c < 48; ++c) { float d = v[c] - mu; var += d * d; }
        var *= (1.f / 48.f);
        const float rs = rsqrtf(var + 1e-5f);
        #pragma unroll
        for (int c = 0; c < 48; ++c)
            aB[tid][c] = f2bf((v[c] - mu) * rs * gamma2[c] + beta2[c]);
        #pragma unroll
        for (int k = 48; k < 64; ++k) aB[tid][k] = 0;
    }
    __syncthreads();

    const int w = tid >> 6;        // wave -> token row-tile
    const int l = tid & 63;
    const int m = l & 15;          // D col / A row
    const int q = l >> 4;          // quad

    // ---- GEMM1: h = gelu(a @ w1^T + b1) ----
    const bfrag A0 = *reinterpret_cast<const bfrag*>(&aB[w * 16 + m][q * 8]);
    const bfrag A1 = *reinterpret_cast<const bfrag*>(&aB[w * 16 + m][32 + q * 8]);
    #pragma unroll
    for (int ct = 0; ct < 12; ++ct) {
        const int n = ct * 16 + m;
        const bfrag B0 = *reinterpret_cast<const bfrag*>(&w1[n * 64 + q * 8]);
        const bfrag B1 = *reinterpret_cast<const bfrag*>(&w1[n * 64 + 32 + q * 8]);
        f32x4 d = {0.f, 0.f, 0.f, 0.f};
        d = __builtin_amdgcn_mfma_f32_16x16x32_bf16(A0, B0, d, 0, 0, 0);
        d = __builtin_amdgcn_mfma_f32_16x16x32_bf16(A1, B1, d, 0, 0, 0);
        const float bias = fc1_b[n];
        #pragma unroll
        for (int i = 0; i < 4; ++i) {
            const float hv = d[i] + bias;
            const float ge = 0.5f * hv * (1.f + erff(hv * 0.70710678118654752f));
            hB[w * 16 + q * 4 + i][n] = f2bf(ge);
        }
    }
    __syncthreads();

    // ---- GEMM2: out += h @ w2^T + b2 + residual ----
    #pragma unroll
    for (int ct = 0; ct < 3; ++ct) {
        f32x4 d = {0.f, 0.f, 0.f, 0.f};
        #pragma unroll
        for (int kt = 0; kt < 6; ++kt) {
            const bfrag a = *reinterpret_cast<const bfrag*>(&hB[w * 16 + m][kt * 32 + q * 8]);
            const bfrag bb = *reinterpret_cast<const bfrag*>(&w2[(ct * 16 + m) * 192 + kt * 32 + q * 8]);
            d = __builtin_amdgcn_mfma_f32_16x16x32_bf16(a, bb, d, 0, 0, 0);
        }
        const int c = ct * 16 + m;
        const float bias = fc2_b[c];
        #pragma unroll
        for (int i = 0; i < 4; ++i) {
            const size_t g = tok0 + w * 16 + q * 4 + i;
            xio[g * 48 + c] += d[i] + bias;
        }
    }
}

extern "C" void kernel_launch(void* const* d_in, const int* in_sizes, int n_in,
                              void* d_out, int out_size, void* d_ws, size_t ws_size,
                              hipStream_t stream)
{
    (void)in_sizes; (void)n_in; (void)out_size; (void)ws_size;
    const float* x      = (const float*)d_in[0];
    const float* gamma1 = (const float*)d_in[1];
    const float* beta1  = (const float*)d_in[2];
    const float* qkv_w  = (const float*)d_in[3];
    const float* qkv_b  = (const float*)d_in[4];
    const float* rpb_t  = (const float*)d_in[5];
    const float* wf     = (const float*)d_in[6];
    const float* se_w1  = (const float*)d_in[7];
    const float* se_b1  = (const float*)d_in[8];
    const float* se_w2  = (const float*)d_in[9];
    const float* se_b2  = (const float*)d_in[10];
    const float* proj_w = (const float*)d_in[11];
    const float* proj_b = (const float*)d_in[12];
    const float* gamma2 = (const float*)d_in[13];
    const float* beta2  = (const float*)d_in[14];
    const float* fc1_w  = (const float*)d_in[15];
    const float* fc1_b  = (const float*)d_in[16];
    const float* fc2_w  = (const float*)d_in[17];
    const float* fc2_b  = (const float*)d_in[18];
    float* out = (float*)d_out;
    unsigned short* wsb = (unsigned short*)d_ws;
    const unsigned short* w1p = wsb;             // 192*64
    const unsigned short* w2p = wsb + 192 * 64;  // 48*192

    prep_weights<<<84, 256, 0, stream>>>(fc1_w, fc2_w, wsb);
    win_kernel<<<8192, 256, 0, stream>>>(x, gamma1, beta1, qkv_w, qkv_b, rpb_t, wf,
                                         se_w1, se_b1, se_w2, se_b2, proj_w, proj_b, out);
    mlp_mfma<<<8192, 256, 0, stream>>>(out, gamma2, beta2, w1p, w2p, fc1_b, fc2_b);
}

// Round 4
// 594.396 us; speedup vs baseline: 3.1071x; 1.3385x over previous
//
#include <hip/hip_runtime.h>

// SwinTransformerBlock: B=8, H=W=256, C=48, NH=3, WS=8, SS=4, N=64, HID=192
// fp32 in/out; all GEMMs via bf16 MFMA 16x16x32, fp32 accumulate.

typedef short bfrag __attribute__((ext_vector_type(8)));   // 8 bf16 (4 VGPRs)
typedef float f32x4 __attribute__((ext_vector_type(4)));

__device__ __forceinline__ unsigned short f2bf(float f) {
    union { float f; unsigned u; } v; v.f = f;
    unsigned r = v.u + 0x7fffu + ((v.u >> 16) & 1u);   // RNE
    return (unsigned short)(r >> 16);
}
__device__ __forceinline__ float bf2f(unsigned short u) {
    union { unsigned i; float f; } v; v.i = ((unsigned)u) << 16; return v.f;
}

// ---------------- kernel 0: prep bf16 weights in d_ws ----------------
// u16 layout: w1p[192][64] | w2p[48][192] | qkvw[144][64] (q rows x0.25) | projw[48][64]
// then f32 qkvb[144] (q part x0.25)
#define WS_W1   0
#define WS_W2   12288
#define WS_QKVW 21504
#define WS_PROJ 30720
#define WS_QKVB 33792   // f32 from here (u16 offset)
__global__ __launch_bounds__(256) void prep_weights(
    const float* __restrict__ fc1_w, const float* __restrict__ fc2_w,
    const float* __restrict__ qkv_w, const float* __restrict__ qkv_b,
    const float* __restrict__ proj_w,
    unsigned short* __restrict__ ws)
{
    int idx = blockIdx.x * 256 + threadIdx.x;
    if (idx < 12288) {                       // fc1 [192][48] -> [192][64]
        int o = idx >> 6, k = idx & 63;
        ws[WS_W1 + idx] = (k < 48) ? f2bf(fc1_w[o * 48 + k]) : 0;
    } else if (idx < 21504) {                // fc2 [48][192] as-is
        int j = idx - 12288;
        ws[WS_W2 + j] = f2bf(fc2_w[j]);
    } else if (idx < 30720) {                // qkv [144][48] -> [144][64], q x0.25
        int j = idx - 21504;
        int n = j >> 6, k = j & 63;
        float v = (k < 48) ? qkv_w[n * 48 + k] : 0.f;
        if (n < 48) v *= 0.25f;
        ws[WS_QKVW + j] = f2bf(v);
    } else if (idx < 33792) {                // proj [48][48] -> [48][64]
        int j = idx - 30720;
        int n = j >> 6, k = j & 63;
        ws[WS_PROJ + j] = (k < 48) ? f2bf(proj_w[n * 48 + k]) : 0;
    } else if (idx < 33792 + 144) {
        int j = idx - 33792;
        float* bb = reinterpret_cast<float*>(ws + WS_QKVB);
        bb[j] = qkv_b[j] * (j < 48 ? 0.25f : 1.f);
    }
}

// ---------------- kernel 1: per-window block, fully MFMA ----------------
__global__ __launch_bounds__(256, 2) void win_kernel(
    const float* __restrict__ x,
    const float* __restrict__ gamma1,
    const float* __restrict__ beta1,
    const unsigned short* __restrict__ wsb,   // prepped weights
    const float* __restrict__ rpb_t,
    const float* __restrict__ wf,
    const float* __restrict__ se_w1,
    const float* __restrict__ se_b1,
    const float* __restrict__ se_w2,
    const float* __restrict__ se_b2,
    const float* __restrict__ proj_b,
    float* __restrict__ out)
{
    __shared__ __align__(16) unsigned short xw_bf[64][72];   // LN'd, cols 48..63 zero
    __shared__ __align__(16) unsigned short Qp[64][104];     // per-head 32-slots, odd-16 zero
    __shared__ __align__(16) unsigned short Kp[64][104];     // same; reused as ao (cols 0..47 + zero 48..63)
    __shared__ __align__(16) unsigned short vT[48][72];      // V transposed [d][token]
    __shared__ __align__(16) unsigned short P[3][64][72];    // exp(S) bf16; reused as po f32[64][52]
    __shared__ float rpb_s[675];
    __shared__ float rsum_s[192];                            // [h][n]
    __shared__ float se_c[48], se_buf[48];
    __shared__ int   reg_id[64];

    const int tid = threadIdx.x;
    const int blk = blockIdx.x;
    const int bb = blk >> 10;
    const int wi = (blk >> 5) & 31;
    const int wj = blk & 31;

    const int w = tid >> 6;       // wave
    const int l = tid & 63;
    const int m = l & 15;
    const int q = l >> 4;
    const int q4 = q * 4;

    for (int i = tid; i < 675; i += 256) rpb_s[i] = rpb_t[i];

    // zero pads
    {
        unsigned* xw32 = reinterpret_cast<unsigned*>(&xw_bf[0][0]);
        unsigned* Qp32 = reinterpret_cast<unsigned*>(&Qp[0][0]);
        unsigned* Kp32 = reinterpret_cast<unsigned*>(&Kp[0][0]);
        for (int i = tid; i < 512; i += 256) {
            int r = i >> 3, d = 24 + (i & 7);
            xw32[r * 36 + d] = 0;
        }
        for (int i = tid; i < 1536; i += 256) {
            int r = i / 24, j = i % 24;
            int h = j >> 3, dd = h * 16 + 8 + (j & 7);
            Qp32[r * 52 + dd] = 0;
            Kp32[r * 52 + dd] = 0;
        }
    }

    // ---- LN1 + shifted gather: thread = (token, quarter) ----
    const int t  = tid >> 2, part = tid & 3;
    const int ti = t >> 3, tj = t & 7;
    const int si = wi * 8 + ti, sj = wj * 8 + tj;
    const int oi = (si + 4) & 255, oj = (sj + 4) & 255;
    const int g  = (bb << 16) + (oi << 8) + oj;
    if (part == 0) {
        const int rr = si < 248 ? 0 : (si < 252 ? 1 : 2);
        const int rc = sj < 248 ? 0 : (sj < 252 ? 1 : 2);
        reg_id[t] = rr * 3 + rc;
    }
    float4 vr[3];
    {
        const float4* p4 = reinterpret_cast<const float4*>(x + (size_t)g * 48 + part * 12);
        vr[0] = p4[0]; vr[1] = p4[1]; vr[2] = p4[2];
        float s = 0.f, ss = 0.f;
        #pragma unroll
        for (int i = 0; i < 3; ++i) {
            s  += vr[i].x + vr[i].y + vr[i].z + vr[i].w;
            ss += vr[i].x*vr[i].x + vr[i].y*vr[i].y + vr[i].z*vr[i].z + vr[i].w*vr[i].w;
        }
        s  += __shfl_xor(s, 1);  s  += __shfl_xor(s, 2);
        ss += __shfl_xor(ss, 1); ss += __shfl_xor(ss, 2);
        const float mu = s * (1.f / 48.f);
        const float var = ss * (1.f / 48.f) - mu * mu;
        const float rs = rsqrtf(var + 1e-5f);
        const float* vv = reinterpret_cast<const float*>(vr);
        #pragma unroll
        for (int j = 0; j < 12; ++j) {
            const int c = part * 12 + j;
            xw_bf[t][c] = f2bf((vv[j] - mu) * rs * gamma1[c] + beta1[c]);
        }
    }
    __syncthreads();

    // ---- qkv GEMM: 36 tiles (4 rt x 9 ct), K=64 (padded) ----
    const float* qkvb = reinterpret_cast<const float*>(wsb + WS_QKVB);
    for (int tt = w; tt < 36; tt += 4) {
        const int rt = tt / 9, ct = tt % 9;
        const bfrag A0 = *reinterpret_cast<const bfrag*>(&xw_bf[rt * 16 + m][q * 8]);
        const bfrag A1 = *reinterpret_cast<const bfrag*>(&xw_bf[rt * 16 + m][32 + q * 8]);
        const int n = ct * 16 + m;
        const bfrag B0 = *reinterpret_cast<const bfrag*>(&wsb[WS_QKVW + n * 64 + q * 8]);
        const bfrag B1 = *reinterpret_cast<const bfrag*>(&wsb[WS_QKVW + n * 64 + 32 + q * 8]);
        f32x4 d = {0.f, 0.f, 0.f, 0.f};
        d = __builtin_amdgcn_mfma_f32_16x16x32_bf16(A0, B0, d, 0, 0, 0);
        d = __builtin_amdgcn_mfma_f32_16x16x32_bf16(A1, B1, d, 0, 0, 0);
        const float bias = qkvb[n];
        #pragma unroll
        for (int i = 0; i < 4; ++i) {
            const int row = rt * 16 + q4 + i;
            const unsigned short vb = f2bf(d[i] + bias);
            if (ct < 3)      Qp[row][ct * 32 + m] = vb;
            else if (ct < 6) Kp[row][(ct - 3) * 32 + m] = vb;
            else             vT[(ct - 6) * 16 + m][row] = vb;
        }
    }
    __syncthreads();

    // ---- SE (uses bf16 xw; tiny) ----
    if (tid < 48) {
        float s = 0.f;
        #pragma unroll 8
        for (int k = 0; k < 64; ++k) s += bf2f(xw_bf[k][tid]);
        se_c[tid] = s * (1.f / 64.f);
    }
    __syncthreads();
    if (tid < 48) {
        float r1[3];
        #pragma unroll
        for (int r = 0; r < 3; ++r) {
            float s = se_b1[r];
            #pragma unroll 8
            for (int c = 0; c < 48; ++c) s += se_c[c] * se_w1[r * 48 + c];
            r1[r] = fmaxf(s, 0.f);
        }
        float s2 = se_b2[tid];
        #pragma unroll
        for (int r = 0; r < 3; ++r) s2 += r1[r] * se_w2[tid * 3 + r];
        se_buf[tid] = wf[0] / (1.f + __expf(-s2));
    }
    __syncthreads();

    // ---- phase A: S = Q K^T (per head, K=32 w/ zero slots), exp, row-sums ----
    for (int j = 0; j < 3; ++j) {
        const int s = w * 3 + j;
        const int h = s >> 2, rt = s & 3;
        const bfrag Aq = *reinterpret_cast<const bfrag*>(&Qp[rt * 16 + m][h * 32 + q * 8]);
        float psum[4] = {0.f, 0.f, 0.f, 0.f};
        #pragma unroll
        for (int ct = 0; ct < 4; ++ct) {
            const bfrag Bk = *reinterpret_cast<const bfrag*>(&Kp[ct * 16 + m][h * 32 + q * 8]);
            f32x4 d = {0.f, 0.f, 0.f, 0.f};
            d = __builtin_amdgcn_mfma_f32_16x16x32_bf16(Aq, Bk, d, 0, 0, 0);
            const int mc = ct * 16 + m;            // key token
            const int i_m = mc >> 3, j_m = mc & 7;
            const int rm = reg_id[mc];
            #pragma unroll
            for (int i = 0; i < 4; ++i) {
                const int n = rt * 16 + q4 + i;    // query token
                const int i_n = n >> 3, j_n = n & 7;
                float sc = d[i] + rpb_s[((i_n - i_m + 7) * 15 + (j_n - j_m + 7)) * 3 + h];
                if (reg_id[n] != rm) sc -= 100.f;
                const float p = __expf(sc);
                psum[i] += p;
                P[h][n][mc] = f2bf(p);
            }
        }
        #pragma unroll
        for (int i = 0; i < 4; ++i) {
            float v = psum[i];
            v += __shfl_xor(v, 1); v += __shfl_xor(v, 2);
            v += __shfl_xor(v, 4); v += __shfl_xor(v, 8);
            if (m == 0) rsum_s[h * 64 + rt * 16 + q4 + i] = v;
        }
    }
    __syncthreads();

    // ---- phase B: O = P V (K=64), normalize, +SE, write ao into Kp ----
    for (int j = 0; j < 3; ++j) {
        const int s = w * 3 + j;
        const int h = s >> 2, rt = s & 3;
        const bfrag A0 = *reinterpret_cast<const bfrag*>(&P[h][rt * 16 + m][q * 8]);
        const bfrag A1 = *reinterpret_cast<const bfrag*>(&P[h][rt * 16 + m][32 + q * 8]);
        const bfrag B0 = *reinterpret_cast<const bfrag*>(&vT[h * 16 + m][q * 8]);
        const bfrag B1 = *reinterpret_cast<const bfrag*>(&vT[h * 16 + m][32 + q * 8]);
        f32x4 d = {0.f, 0.f, 0.f, 0.f};
        d = __builtin_amdgcn_mfma_f32_16x16x32_bf16(A0, B0, d, 0, 0, 0);
        d = __builtin_amdgcn_mfma_f32_16x16x32_bf16(A1, B1, d, 0, 0, 0);
        const int c = h * 16 + m;
        const float sew = se_buf[c];
        #pragma unroll
        for (int i = 0; i < 4; ++i) {
            const int n = rt * 16 + q4 + i;
            const float o = d[i] / rsum_s[h * 64 + n];
            Kp[n][c] = f2bf(o + sew * bf2f(xw_bf[n][c]));   // ao; cols 48..63 stay zero
        }
    }
    __syncthreads();

    // ---- proj: 12 tiles (4 rt x 3 ct), K=64 over ao(Kp) ----
    float* po = reinterpret_cast<float*>(&P[0][0][0]);       // [64][52] f32 overlay
    for (int tt = w; tt < 12; tt += 4) {
        const int rt = tt / 3, ct = tt % 3;
        const bfrag A0 = *reinterpret_cast<const bfrag*>(&Kp[rt * 16 + m][q * 8]);
        const bfrag A1 = *reinterpret_cast<const bfrag*>(&Kp[rt * 16 + m][32 + q * 8]);
        const int n = ct * 16 + m;
        const bfrag B0 = *reinterpret_cast<const bfrag*>(&wsb[WS_PROJ + n * 64 + q * 8]);
        const bfrag B1 = *reinterpret_cast<const bfrag*>(&wsb[WS_PROJ + n * 64 + 32 + q * 8]);
        f32x4 d = {0.f, 0.f, 0.f, 0.f};
        d = __builtin_amdgcn_mfma_f32_16x16x32_bf16(A0, B0, d, 0, 0, 0);
        d = __builtin_amdgcn_mfma_f32_16x16x32_bf16(A1, B1, d, 0, 0, 0);
        const float bias = proj_b[n];
        #pragma unroll
        for (int i = 0; i < 4; ++i)
            po[(rt * 16 + q4 + i) * 52 + n] = d[i] + bias;
    }
    __syncthreads();

    // ---- residual (regs) + coalesced store ----
    {
        float4* o4 = reinterpret_cast<float4*>(out + (size_t)g * 48 + part * 12);
        const float4* p4 = reinterpret_cast<const float4*>(&po[t * 52 + part * 12]);
        #pragma unroll
        for (int jj = 0; jj < 3; ++jj) {
            float4 r = p4[jj];
            r.x += vr[jj].x; r.y += vr[jj].y; r.z += vr[jj].z; r.w += vr[jj].w;
            o4[jj] = r;
        }
    }
}

// ---------------- kernel 2: MLP via bf16 MFMA, in-place on out ----------------
__global__ __launch_bounds__(256, 3) void mlp_mfma(
    float* __restrict__ xio,
    const float* __restrict__ gamma2,
    const float* __restrict__ beta2,
    const unsigned short* __restrict__ wsb,
    const float* __restrict__ fc1_b,
    const float* __restrict__ fc2_b)
{
    __shared__ __align__(16) unsigned short aB[64][72];    // LN'd, cols 48..63 zero
    __shared__ __align__(16) unsigned short hB[64][200];   // gelu(fc1)
    __shared__ float po[64][52];
    const int tid = threadIdx.x;
    const size_t tok0 = (size_t)blockIdx.x * 64;

    // ---- LN2: thread = (token, quarter); residual kept in regs ----
    const int t = tid >> 2, part = tid & 3;
    float4 vr[3];
    {
        const float4* p4 = reinterpret_cast<const float4*>(xio + (tok0 + t) * 48 + part * 12);
        vr[0] = p4[0]; vr[1] = p4[1]; vr[2] = p4[2];
        float s = 0.f, ss = 0.f;
        #pragma unroll
        for (int i = 0; i < 3; ++i) {
            s  += vr[i].x + vr[i].y + vr[i].z + vr[i].w;
            ss += vr[i].x*vr[i].x + vr[i].y*vr[i].y + vr[i].z*vr[i].z + vr[i].w*vr[i].w;
        }
        s  += __shfl_xor(s, 1);  s  += __shfl_xor(s, 2);
        ss += __shfl_xor(ss, 1); ss += __shfl_xor(ss, 2);
        const float mu = s * (1.f / 48.f);
        const float var = ss * (1.f / 48.f) - mu * mu;
        const float rs = rsqrtf(var + 1e-5f);
        const float* vv = reinterpret_cast<const float*>(vr);
        #pragma unroll
        for (int j = 0; j < 12; ++j) {
            const int c = part * 12 + j;
            aB[t][c] = f2bf((vv[j] - mu) * rs * gamma2[c] + beta2[c]);
        }
        if (part == 0) {
            unsigned* a32 = reinterpret_cast<unsigned*>(&aB[t][0]);
            #pragma unroll
            for (int k = 24; k < 32; ++k) a32[k] = 0;
        }
    }
    __syncthreads();

    const int w = tid >> 6;
    const int l = tid & 63;
    const int m = l & 15;
    const int q = l >> 4;

    // ---- GEMM1: h = gelu(a @ w1^T + b1) ----
    const bfrag A0 = *reinterpret_cast<const bfrag*>(&aB[w * 16 + m][q * 8]);
    const bfrag A1 = *reinterpret_cast<const bfrag*>(&aB[w * 16 + m][32 + q * 8]);
    #pragma unroll
    for (int ct = 0; ct < 12; ++ct) {
        const int n = ct * 16 + m;
        const bfrag B0 = *reinterpret_cast<const bfrag*>(&wsb[WS_W1 + n * 64 + q * 8]);
        const bfrag B1 = *reinterpret_cast<const bfrag*>(&wsb[WS_W1 + n * 64 + 32 + q * 8]);
        f32x4 d = {0.f, 0.f, 0.f, 0.f};
        d = __builtin_amdgcn_mfma_f32_16x16x32_bf16(A0, B0, d, 0, 0, 0);
        d = __builtin_amdgcn_mfma_f32_16x16x32_bf16(A1, B1, d, 0, 0, 0);
        const float bias = fc1_b[n];
        #pragma unroll
        for (int i = 0; i < 4; ++i) {
            const float hv = d[i] + bias;
            const float ge = 0.5f * hv * (1.f + erff(hv * 0.70710678118654752f));
            hB[w * 16 + q * 4 + i][n] = f2bf(ge);
        }
    }
    __syncthreads();

    // ---- GEMM2: po = h @ w2^T + b2 ----
    #pragma unroll
    for (int ct = 0; ct < 3; ++ct) {
        f32x4 d = {0.f, 0.f, 0.f, 0.f};
        #pragma unroll
        for (int kt = 0; kt < 6; ++kt) {
            const bfrag a  = *reinterpret_cast<const bfrag*>(&hB[w * 16 + m][kt * 32 + q * 8]);
            const bfrag bb = *reinterpret_cast<const bfrag*>(&wsb[WS_W2 + (ct * 16 + m) * 192 + kt * 32 + q * 8]);
            d = __builtin_amdgcn_mfma_f32_16x16x32_bf16(a, bb, d, 0, 0, 0);
        }
        const int c = ct * 16 + m;
        const float bias = fc2_b[c];
        #pragma unroll
        for (int i = 0; i < 4; ++i)
            po[w * 16 + q * 4 + i][c] = d[i] + bias;
    }
    __syncthreads();

    // ---- residual (regs) + coalesced store ----
    {
        float4* o4 = reinterpret_cast<float4*>(xio + (tok0 + t) * 48 + part * 12);
        const float4* p4 = reinterpret_cast<const float4*>(&po[t][part * 12]);
        #pragma unroll
        for (int jj = 0; jj < 3; ++jj) {
            float4 r = p4[jj];
            r.x += vr[jj].x; r.y += vr[jj].y; r.z += vr[jj].z; r.w += vr[jj].w;
            o4[jj] = r;
        }
    }
}

extern "C" void kernel_launch(void* const* d_in, const int* in_sizes, int n_in,
                              void* d_out, int out_size, void* d_ws, size_t ws_size,
                              hipStream_t stream)
{
    (void)in_sizes; (void)n_in; (void)out_size; (void)ws_size;
    const float* x      = (const float*)d_in[0];
    const float* gamma1 = (const float*)d_in[1];
    const float* beta1  = (const float*)d_in[2];
    const float* qkv_w  = (const float*)d_in[3];
    const float* qkv_b  = (const float*)d_in[4];
    const float* rpb_t  = (const float*)d_in[5];
    const float* wf     = (const float*)d_in[6];
    const float* se_w1  = (const float*)d_in[7];
    const float* se_b1  = (const float*)d_in[8];
    const float* se_w2  = (const float*)d_in[9];
    const float* se_b2  = (const float*)d_in[10];
    const float* proj_w = (const float*)d_in[11];
    const float* proj_b = (const float*)d_in[12];
    const float* gamma2 = (const float*)d_in[13];
    const float* beta2  = (const float*)d_in[14];
    const float* fc1_w  = (const float*)d_in[15];
    const float* fc1_b  = (const float*)d_in[16];
    const float* fc2_w  = (const float*)d_in[17];
    const float* fc2_b  = (const float*)d_in[18];
    float* out = (float*)d_out;
    unsigned short* wsb = (unsigned short*)d_ws;

    prep_weights<<<133, 256, 0, stream>>>(fc1_w, fc2_w, qkv_w, qkv_b, proj_w, wsb);
    win_kernel<<<8192, 256, 0, stream>>>(x, gamma1, beta1, wsb, rpb_t, wf,
                                         se_w1, se_b1, se_w2, se_b2, proj_b, out);
    mlp_mfma<<<8192, 256, 0, stream>>>(out, gamma2, beta2, wsb, fc1_b, fc2_b);
}

// Round 5
// 507.791 us; speedup vs baseline: 3.6371x; 1.1706x over previous
//
#include <hip/hip_runtime.h>

// SwinTransformerBlock: B=8, H=W=256, C=48, NH=3, WS=8, SS=4, N=64, HID=192
// fp32 in/out; all GEMMs bf16 MFMA 16x16x32 with "transposed D" (D=[feat][token])
// so epilogues write 4 consecutive features per lane (packed b64 / float4 RMW).

typedef short bfrag __attribute__((ext_vector_type(8)));   // 8 bf16 (4 VGPRs)
typedef float f32x4 __attribute__((ext_vector_type(4)));

__device__ __forceinline__ unsigned short f2bf(float f) {
    union { float f; unsigned u; } v; v.f = f;
    unsigned r = v.u + 0x7fffu + ((v.u >> 16) & 1u);   // RNE
    return (unsigned short)(r >> 16);
}
__device__ __forceinline__ unsigned pk2(float a, float b) {
    return (unsigned)f2bf(a) | ((unsigned)f2bf(b) << 16);
}
__device__ __forceinline__ void bf2x(unsigned u, float& lo, float& hi) {
    union { unsigned i; float f; } a, b;
    a.i = u << 16; b.i = u & 0xffff0000u;
    lo = a.f; hi = b.f;
}

// ---------------- kernel 0: prep bf16 weights in d_ws ----------------
// u16 layout: w1p[192][64] | w2p[48][192] | qkvw[144][64] (q rows x0.25) | projw[48][64]
// then f32 qkvb[144] (q part x0.25)
#define WS_W1   0
#define WS_W2   12288
#define WS_QKVW 21504
#define WS_PROJ 30720
#define WS_QKVB 33792   // f32 from here (u16 offset)
__global__ __launch_bounds__(256) void prep_weights(
    const float* __restrict__ fc1_w, const float* __restrict__ fc2_w,
    const float* __restrict__ qkv_w, const float* __restrict__ qkv_b,
    const float* __restrict__ proj_w,
    unsigned short* __restrict__ ws)
{
    int idx = blockIdx.x * 256 + threadIdx.x;
    if (idx < 12288) {                       // fc1 [192][48] -> [192][64]
        int o = idx >> 6, k = idx & 63;
        ws[WS_W1 + idx] = (k < 48) ? f2bf(fc1_w[o * 48 + k]) : 0;
    } else if (idx < 21504) {                // fc2 [48][192] as-is
        int j = idx - 12288;
        ws[WS_W2 + j] = f2bf(fc2_w[j]);
    } else if (idx < 30720) {                // qkv [144][48] -> [144][64], q x0.25
        int j = idx - 21504;
        int n = j >> 6, k = j & 63;
        float v = (k < 48) ? qkv_w[n * 48 + k] : 0.f;
        if (n < 48) v *= 0.25f;
        ws[WS_QKVW + j] = f2bf(v);
    } else if (idx < 33792) {                // proj [48][48] -> [48][64]
        int j = idx - 30720;
        int n = j >> 6, k = j & 63;
        ws[WS_PROJ + j] = (k < 48) ? f2bf(proj_w[n * 48 + k]) : 0;
    } else if (idx < 33792 + 144) {
        int j = idx - 33792;
        float* bb = reinterpret_cast<float*>(ws + WS_QKVB);
        bb[j] = qkv_b[j] * (j < 48 ? 0.25f : 1.f);
    }
}

// ---------------- kernel 1: per-window block ----------------
__global__ __launch_bounds__(256, 3) void win_kernel(
    const float* __restrict__ x,
    const float* __restrict__ gamma1,
    const float* __restrict__ beta1,
    const unsigned short* __restrict__ wsb,
    const float* __restrict__ rpb_t,
    const float* __restrict__ wf,
    const float* __restrict__ se_w1,
    const float* __restrict__ se_b1,
    const float* __restrict__ se_w2,
    const float* __restrict__ se_b2,
    const float* __restrict__ proj_b,
    float* __restrict__ out)
{
    __shared__ __align__(16) unsigned short xw[64][56];   // LN'd tokens [tok][ch]
    __shared__ __align__(16) unsigned short Qh[64][56];   // [tok][head*16+d]
    __shared__ __align__(16) unsigned short Kh[64][56];
    __shared__ __align__(16) unsigned short ao[64][56];   // attn out + SE [tok][ch]
    __shared__ __align__(16) unsigned short vT[48][72];   // [feat][tok]
    __shared__ __align__(16) unsigned short Pw[4][16][72];// per-wave P [query][key]
    __shared__ __align__(16) unsigned short zbuf[32];     // shared zero fragment
    __shared__ float rpb_s[675];
    __shared__ float se_c[48], se_buf[48];
    __shared__ int   gidx[64];

    const int tid = threadIdx.x;
    const int blk = blockIdx.x;
    const int bb = blk >> 10;
    const int wi = (blk >> 5) & 31;
    const int wj = blk & 31;

    const int w = tid >> 6;       // wave
    const int l = tid & 63;
    const int m = l & 15;
    const int q = l >> 4;
    const int q4 = q * 4;

    for (int i = tid; i < 675; i += 256) rpb_s[i] = rpb_t[i];
    if (tid < 32) zbuf[tid] = 0;

    // ---- LN1 + shifted gather: thread = (token, quarter) ----
    const int t = tid >> 2, part = tid & 3;
    {
        const int ti = t >> 3, tj = t & 7;
        const int si = wi * 8 + ti, sj = wj * 8 + tj;
        const int oi = (si + 4) & 255, oj = (sj + 4) & 255;
        const int g = (bb << 16) + (oi << 8) + oj;
        if (part == 0) gidx[t] = g;
        const float4* p4 = reinterpret_cast<const float4*>(x + (size_t)g * 48 + part * 12);
        float4 vr0 = p4[0], vr1 = p4[1], vr2 = p4[2];
        float s = vr0.x + vr0.y + vr0.z + vr0.w + vr1.x + vr1.y + vr1.z + vr1.w
                + vr2.x + vr2.y + vr2.z + vr2.w;
        float ss = vr0.x*vr0.x + vr0.y*vr0.y + vr0.z*vr0.z + vr0.w*vr0.w
                 + vr1.x*vr1.x + vr1.y*vr1.y + vr1.z*vr1.z + vr1.w*vr1.w
                 + vr2.x*vr2.x + vr2.y*vr2.y + vr2.z*vr2.z + vr2.w*vr2.w;
        s  += __shfl_xor(s, 1);  s  += __shfl_xor(s, 2);
        ss += __shfl_xor(ss, 1); ss += __shfl_xor(ss, 2);
        const float mu = s * (1.f / 48.f);
        const float var = ss * (1.f / 48.f) - mu * mu;
        const float rs = rsqrtf(var + 1e-5f);
        float vv[12];
        *reinterpret_cast<float4*>(vv + 0) = vr0;
        *reinterpret_cast<float4*>(vv + 4) = vr1;
        *reinterpret_cast<float4*>(vv + 8) = vr2;
        float ln[12];
        #pragma unroll
        for (int jj = 0; jj < 12; ++jj) {
            const int c = part * 12 + jj;
            ln[jj] = (vv[jj] - mu) * rs * gamma1[c] + beta1[c];
        }
        unsigned short* dst = &xw[t][part * 12];
        #pragma unroll
        for (int jj = 0; jj < 3; ++jj) {
            uint2 u; u.x = pk2(ln[jj*4+0], ln[jj*4+1]); u.y = pk2(ln[jj*4+2], ln[jj*4+3]);
            *reinterpret_cast<uint2*>(dst + jj * 4) = u;
        }
    }
    __syncthreads();

    // ---- qkv (waves 0-2, 12 tiles each) ; SE stage (wave 3) ----
    if (w < 3) {
        const float* qkvb = reinterpret_cast<const float*>(wsb + WS_QKVB);
        for (int tt = w; tt < 36; tt += 3) {
            const int ct = tt / 4, rt = tt & 3;
            bfrag B0 = *reinterpret_cast<const bfrag*>(&xw[rt * 16 + m][q * 8]);
            bfrag B1 = (q < 2) ? *reinterpret_cast<const bfrag*>(&xw[rt * 16 + m][32 + q * 8])
                               : *reinterpret_cast<const bfrag*>(&zbuf[(q - 2) * 8]);
            bfrag A0 = *reinterpret_cast<const bfrag*>(&wsb[WS_QKVW + (ct * 16 + m) * 64 + q * 8]);
            bfrag A1 = *reinterpret_cast<const bfrag*>(&wsb[WS_QKVW + (ct * 16 + m) * 64 + 32 + q * 8]);
            f32x4 d = {0.f, 0.f, 0.f, 0.f};
            d = __builtin_amdgcn_mfma_f32_16x16x32_bf16(A0, B0, d, 0, 0, 0);
            d = __builtin_amdgcn_mfma_f32_16x16x32_bf16(A1, B1, d, 0, 0, 0);
            const float4 bias = *reinterpret_cast<const float4*>(&qkvb[ct * 16 + q4]);
            float v0 = d[0] + bias.x, v1 = d[1] + bias.y, v2 = d[2] + bias.z, v3 = d[3] + bias.w;
            const int tk = rt * 16 + m;
            if (ct < 3) {
                uint2 u; u.x = pk2(v0, v1); u.y = pk2(v2, v3);
                *reinterpret_cast<uint2*>(&Qh[tk][ct * 16 + q4]) = u;
            } else if (ct < 6) {
                uint2 u; u.x = pk2(v0, v1); u.y = pk2(v2, v3);
                *reinterpret_cast<uint2*>(&Kh[tk][(ct - 3) * 16 + q4]) = u;
            } else {
                float vv4[4] = {v0, v1, v2, v3};
                #pragma unroll
                for (int ii = 0; ii < 4; ++ii) {
                    const int i = (ii + q) & 3;            // rotate rows -> 2-way banks
                    vT[(ct - 6) * 16 + q4 + i][tk] = f2bf(vv4[i]);
                }
            }
        }
    } else if (l < 48) {
        float s = 0.f;
        #pragma unroll 8
        for (int k = 0; k < 64; ++k) {
            union { unsigned i; float f; } u; u.i = ((unsigned)xw[k][l]) << 16;
            s += u.f;
        }
        se_c[l] = s * (1.f / 64.f);
    }
    if (w == 3) {
        __builtin_amdgcn_wave_barrier();
        if (l < 48) {
            float r1[3];
            #pragma unroll
            for (int r = 0; r < 3; ++r) {
                float s = se_b1[r];
                #pragma unroll 8
                for (int c = 0; c < 48; ++c) s += se_c[c] * se_w1[r * 48 + c];
                r1[r] = fmaxf(s, 0.f);
            }
            float s2 = se_b2[l];
            #pragma unroll
            for (int r = 0; r < 3; ++r) s2 += r1[r] * se_w2[l * 3 + r];
            se_buf[l] = wf[0] / (1.f + __expf(-s2));
        }
    }
    __syncthreads();

    // ---- fused attention: 3 slots per wave, no barriers (Pw wave-local) ----
    const bool masked_blk = (wi == 31) || (wj == 31);
    for (int j = 0; j < 3; ++j) {
        const int s = w * 3 + j;
        const int h = s >> 2, rt = s & 3;
        const int tq = rt * 16 + m;                 // query token (= D col)
        const int qi = tq >> 3, qj = tq & 7;
        const int rrq = (wi == 31) ? ((qi >= 4) ? 2 : 1) : 0;
        const int rcq = (wj == 31) ? ((qj >= 4) ? 2 : 1) : 0;
        bfrag Bq = (q < 2) ? *reinterpret_cast<const bfrag*>(&Qh[tq][h * 16 + q * 8])
                           : *reinterpret_cast<const bfrag*>(&zbuf[(q - 2) * 8]);
        float rtot = 0.f;
        #pragma unroll
        for (int ct = 0; ct < 4; ++ct) {
            bfrag Ak = (q < 2) ? *reinterpret_cast<const bfrag*>(&Kh[ct * 16 + m][h * 16 + q * 8])
                               : *reinterpret_cast<const bfrag*>(&zbuf[(q - 2) * 8]);
            f32x4 d = {0.f, 0.f, 0.f, 0.f};
            d = __builtin_amdgcn_mfma_f32_16x16x32_bf16(Ak, Bq, d, 0, 0, 0);
            float pv[4];
            #pragma unroll
            for (int i = 0; i < 4; ++i) {
                const int tk = ct * 16 + q4 + i;    // key token (= D row)
                const int ki = tk >> 3, kj = tk & 7;
                float sc = d[i] + rpb_s[((qi - ki + 7) * 15 + (qj - kj + 7)) * 3 + h];
                if (masked_blk) {
                    const int rrk = (wi == 31) ? ((ki >= 4) ? 2 : 1) : 0;
                    const int rck = (wj == 31) ? ((kj >= 4) ? 2 : 1) : 0;
                    if ((rrk != rrq) || (rck != rcq)) sc -= 100.f;
                }
                const float p = __expf(sc);
                rtot += p;
                pv[i] = p;
            }
            uint2 u; u.x = pk2(pv[0], pv[1]); u.y = pk2(pv[2], pv[3]);
            *reinterpret_cast<uint2*>(&Pw[w][m][ct * 16 + q4]) = u;
        }
        rtot += __shfl_xor(rtot, 16);
        rtot += __shfl_xor(rtot, 32);
        const float rinv = 1.f / rtot;
        // PV: D[vcol][query]
        bfrag Av0 = *reinterpret_cast<const bfrag*>(&vT[h * 16 + m][q * 8]);
        bfrag Av1 = *reinterpret_cast<const bfrag*>(&vT[h * 16 + m][32 + q * 8]);
        bfrag Bp0 = *reinterpret_cast<const bfrag*>(&Pw[w][m][q * 8]);
        bfrag Bp1 = *reinterpret_cast<const bfrag*>(&Pw[w][m][32 + q * 8]);
        f32x4 d = {0.f, 0.f, 0.f, 0.f};
        d = __builtin_amdgcn_mfma_f32_16x16x32_bf16(Av0, Bp0, d, 0, 0, 0);
        d = __builtin_amdgcn_mfma_f32_16x16x32_bf16(Av1, Bp1, d, 0, 0, 0);
        const int c0 = h * 16 + q4;
        const float4 sev = *reinterpret_cast<const float4*>(&se_buf[c0]);
        uint2 xv = *reinterpret_cast<const uint2*>(&xw[tq][c0]);
        float x0, x1, x2, x3;
        bf2x(xv.x, x0, x1); bf2x(xv.y, x2, x3);
        const float o0 = d[0] * rinv + sev.x * x0;
        const float o1 = d[1] * rinv + sev.y * x1;
        const float o2 = d[2] * rinv + sev.z * x2;
        const float o3 = d[3] * rinv + sev.w * x3;
        uint2 u; u.x = pk2(o0, o1); u.y = pk2(o2, o3);
        *reinterpret_cast<uint2*>(&ao[tq][c0]) = u;
    }
    __syncthreads();

    // ---- proj: D[out_ch][token] -> float4 RMW to out (window reverse via gidx) ----
    {
        bfrag B0 = *reinterpret_cast<const bfrag*>(&ao[w * 16 + m][q * 8]);
        bfrag B1 = (q < 2) ? *reinterpret_cast<const bfrag*>(&ao[w * 16 + m][32 + q * 8])
                           : *reinterpret_cast<const bfrag*>(&zbuf[(q - 2) * 8]);
        const int tok = w * 16 + m;
        const int g = gidx[tok];
        #pragma unroll
        for (int ct = 0; ct < 3; ++ct) {
            bfrag A0 = *reinterpret_cast<const bfrag*>(&wsb[WS_PROJ + (ct * 16 + m) * 64 + q * 8]);
            bfrag A1 = *reinterpret_cast<const bfrag*>(&wsb[WS_PROJ + (ct * 16 + m) * 64 + 32 + q * 8]);
            f32x4 d = {0.f, 0.f, 0.f, 0.f};
            d = __builtin_amdgcn_mfma_f32_16x16x32_bf16(A0, B0, d, 0, 0, 0);
            d = __builtin_amdgcn_mfma_f32_16x16x32_bf16(A1, B1, d, 0, 0, 0);
            const int c0 = ct * 16 + q4;
            const float4 bias = *reinterpret_cast<const float4*>(&proj_b[c0]);
            const float4 xr = *reinterpret_cast<const float4*>(&x[(size_t)g * 48 + c0]);
            float4 r;
            r.x = xr.x + d[0] + bias.x;
            r.y = xr.y + d[1] + bias.y;
            r.z = xr.z + d[2] + bias.z;
            r.w = xr.w + d[3] + bias.w;
            *reinterpret_cast<float4*>(&out[(size_t)g * 48 + c0]) = r;
        }
    }
}

// ---------------- kernel 2: MLP, transposed-D MFMA, in-place on out ----------------
__global__ __launch_bounds__(256, 4) void mlp_mfma(
    float* __restrict__ xio,
    const float* __restrict__ gamma2,
    const float* __restrict__ beta2,
    const unsigned short* __restrict__ wsb,
    const float* __restrict__ fc1_b,
    const float* __restrict__ fc2_b)
{
    __shared__ __align__(16) unsigned short aB[64][56];    // LN'd [tok][ch]
    __shared__ __align__(16) unsigned short hB[64][200];   // gelu(fc1) [tok][hid]
    __shared__ __align__(16) unsigned short zbuf[32];
    const int tid = threadIdx.x;
    const size_t tok0 = (size_t)blockIdx.x * 64;

    if (tid < 32) zbuf[tid] = 0;

    // ---- LN2: thread = (token, quarter) ----
    const int t = tid >> 2, part = tid & 3;
    {
        const float4* p4 = reinterpret_cast<const float4*>(xio + (tok0 + t) * 48 + part * 12);
        float4 vr0 = p4[0], vr1 = p4[1], vr2 = p4[2];
        float s = vr0.x + vr0.y + vr0.z + vr0.w + vr1.x + vr1.y + vr1.z + vr1.w
                + vr2.x + vr2.y + vr2.z + vr2.w;
        float ss = vr0.x*vr0.x + vr0.y*vr0.y + vr0.z*vr0.z + vr0.w*vr0.w
                 + vr1.x*vr1.x + vr1.y*vr1.y + vr1.z*vr1.z + vr1.w*vr1.w
                 + vr2.x*vr2.x + vr2.y*vr2.y + vr2.z*vr2.z + vr2.w*vr2.w;
        s  += __shfl_xor(s, 1);  s  += __shfl_xor(s, 2);
        ss += __shfl_xor(ss, 1); ss += __shfl_xor(ss, 2);
        const float mu = s * (1.f / 48.f);
        const float var = ss * (1.f / 48.f) - mu * mu;
        const float rs = rsqrtf(var + 1e-5f);
        float vv[12];
        *reinterpret_cast<float4*>(vv + 0) = vr0;
        *reinterpret_cast<float4*>(vv + 4) = vr1;
        *reinterpret_cast<float4*>(vv + 8) = vr2;
        float ln[12];
        #pragma unroll
        for (int jj = 0; jj < 12; ++jj) {
            const int c = part * 12 + jj;
            ln[jj] = (vv[jj] - mu) * rs * gamma2[c] + beta2[c];
        }
        unsigned short* dst = &aB[t][part * 12];
        #pragma unroll
        for (int jj = 0; jj < 3; ++jj) {
            uint2 u; u.x = pk2(ln[jj*4+0], ln[jj*4+1]); u.y = pk2(ln[jj*4+2], ln[jj*4+3]);
            *reinterpret_cast<uint2*>(dst + jj * 4) = u;
        }
    }
    __syncthreads();

    const int w = tid >> 6;
    const int l = tid & 63;
    const int m = l & 15;
    const int q = l >> 4;
    const int q4 = q * 4;

    // ---- GEMM1: D[hid][tok] = W1 . aB^T ; gelu -> hB ----
    {
        bfrag B0 = *reinterpret_cast<const bfrag*>(&aB[w * 16 + m][q * 8]);
        bfrag B1 = (q < 2) ? *reinterpret_cast<const bfrag*>(&aB[w * 16 + m][32 + q * 8])
                           : *reinterpret_cast<const bfrag*>(&zbuf[(q - 2) * 8]);
        const int tk = w * 16 + m;
        #pragma unroll
        for (int ct = 0; ct < 12; ++ct) {
            bfrag A0 = *reinterpret_cast<const bfrag*>(&wsb[WS_W1 + (ct * 16 + m) * 64 + q * 8]);
            bfrag A1 = *reinterpret_cast<const bfrag*>(&wsb[WS_W1 + (ct * 16 + m) * 64 + 32 + q * 8]);
            f32x4 d = {0.f, 0.f, 0.f, 0.f};
            d = __builtin_amdgcn_mfma_f32_16x16x32_bf16(A0, B0, d, 0, 0, 0);
            d = __builtin_amdgcn_mfma_f32_16x16x32_bf16(A1, B1, d, 0, 0, 0);
            const int f0 = ct * 16 + q4;
            const float4 bias = *reinterpret_cast<const float4*>(&fc1_b[f0]);
            float ge[4];
            #pragma unroll
            for (int i = 0; i < 4; ++i) {
                const float hv = d[i] + (i == 0 ? bias.x : i == 1 ? bias.y : i == 2 ? bias.z : bias.w);
                ge[i] = 0.5f * hv * (1.f + erff(hv * 0.70710678118654752f));
            }
            uint2 u; u.x = pk2(ge[0], ge[1]); u.y = pk2(ge[2], ge[3]);
            *reinterpret_cast<uint2*>(&hB[tk][f0]) = u;
        }
    }
    __syncthreads();

    // ---- GEMM2: D[out_ch][tok] = W2 . hB^T ; float4 RMW residual ----
    {
        f32x4 acc[3];
        #pragma unroll
        for (int ct = 0; ct < 3; ++ct) acc[ct] = (f32x4){0.f, 0.f, 0.f, 0.f};
        #pragma unroll
        for (int kt = 0; kt < 6; ++kt) {
            bfrag Bh = *reinterpret_cast<const bfrag*>(&hB[w * 16 + m][kt * 32 + q * 8]);
            #pragma unroll
            for (int ct = 0; ct < 3; ++ct) {
                bfrag Aw = *reinterpret_cast<const bfrag*>(
                    &wsb[WS_W2 + (ct * 16 + m) * 192 + kt * 32 + q * 8]);
                acc[ct] = __builtin_amdgcn_mfma_f32_16x16x32_bf16(Aw, Bh, acc[ct], 0, 0, 0);
            }
        }
        const size_t tok = tok0 + w * 16 + m;
        #pragma unroll
        for (int ct = 0; ct < 3; ++ct) {
            const int c0 = ct * 16 + q4;
            const float4 bias = *reinterpret_cast<const float4*>(&fc2_b[c0]);
            float4* pp = reinterpret_cast<float4*>(xio + tok * 48 + c0);
            float4 r = *pp;
            r.x += acc[ct][0] + bias.x;
            r.y += acc[ct][1] + bias.y;
            r.z += acc[ct][2] + bias.z;
            r.w += acc[ct][3] + bias.w;
            *pp = r;
        }
    }
}

extern "C" void kernel_launch(void* const* d_in, const int* in_sizes, int n_in,
                              void* d_out, int out_size, void* d_ws, size_t ws_size,
                              hipStream_t stream)
{
    (void)in_sizes; (void)n_in; (void)out_size; (void)ws_size;
    const float* x      = (const float*)d_in[0];
    const float* gamma1 = (const float*)d_in[1];
    const float* beta1  = (const float*)d_in[2];
    const float* qkv_w  = (const float*)d_in[3];
    const float* qkv_b  = (const float*)d_in[4];
    const float* rpb_t  = (const float*)d_in[5];
    const float* wf     = (const float*)d_in[6];
    const float* se_w1  = (const float*)d_in[7];
    const float* se_b1  = (const float*)d_in[8];
    const float* se_w2  = (const float*)d_in[9];
    const float* se_b2  = (const float*)d_in[10];
    const float* proj_w = (const float*)d_in[11];
    const float* proj_b = (const float*)d_in[12];
    const float* gamma2 = (const float*)d_in[13];
    const float* beta2  = (const float*)d_in[14];
    const float* fc1_w  = (const float*)d_in[15];
    const float* fc1_b  = (const float*)d_in[16];
    const float* fc2_w  = (const float*)d_in[17];
    const float* fc2_b  = (const float*)d_in[18];
    float* out = (float*)d_out;
    unsigned short* wsb = (unsigned short*)d_ws;

    prep_weights<<<133, 256, 0, stream>>>(fc1_w, fc2_w, qkv_w, qkv_b, proj_w, wsb);
    win_kernel<<<8192, 256, 0, stream>>>(x, gamma1, beta1, wsb, rpb_t, wf,
                                         se_w1, se_b1, se_w2, se_b2, proj_b, out);
    mlp_mfma<<<8192, 256, 0, stream>>>(out, gamma2, beta2, wsb, fc1_b, fc2_b);
}